// Round 1
// baseline (778.736 us; speedup 1.0000x reference)
//
#include <hip/hip_runtime.h>

#define DEVI __device__ __forceinline__

typedef __attribute__((ext_vector_type(8))) short s16x8;
typedef __attribute__((ext_vector_type(4))) float f32x4;

// np.linspace(1, 168, 32).astype(int64)
__device__ __constant__ int LAGS_C[32] = {
    1,6,11,17,22,27,33,38,44,49,54,60,65,71,76,81,
    87,92,97,103,108,114,119,124,130,135,141,146,151,157,162,168};

DEVI unsigned short f2bf(float f) {
  unsigned u = __float_as_uint(f);
  return (unsigned short)((u + 0x7FFFu + ((u >> 16) & 1u)) >> 16);
}
DEVI unsigned pk2(float a, float b) {
  return (unsigned)f2bf(a) | ((unsigned)f2bf(b) << 16);
}

DEVI f32x4 mfma16(s16x8 a, s16x8 b, f32x4 c) {
  // D==C tied; inline asm avoids builtin signature friction (short8 vs bf16x8)
  asm("v_mfma_f32_16x16x32_bf16 %0, %1, %2, %0" : "+v"(c) : "v"(a), "v"(b));
  return c;
}

// ---------------- xm = mean over D ----------------
__global__ __launch_bounds__(256) void k_mean(const float* __restrict__ x,
                                              float* __restrict__ xm) {
  int row = blockIdx.x * 4 + (threadIdx.x >> 6);
  int lane = threadIdx.x & 63;
  const float4* p = (const float4*)(x + (size_t)row * 512 + lane * 8);
  float4 a = p[0], bq = p[1];
  float s = a.x + a.y + a.z + a.w + bq.x + bq.y + bq.z + bq.w;
#pragma unroll
  for (int off = 32; off; off >>= 1) s += __shfl_xor(s, off, 64);
  if (lane == 0) xm[row] = s * (1.0f / 512.0f);
}

// ---------------- proj_w fp32 -> bf16 ----------------
__global__ __launch_bounds__(256) void k_cvt(const float* __restrict__ pw,
                                             unsigned short* __restrict__ pwb) {
  int i = (blockIdx.x * 256 + threadIdx.x) * 4;
  float4 v = *(const float4*)(pw + i);
  ushort4 o;
  o.x = f2bf(v.x); o.y = f2bf(v.y); o.z = f2bf(v.z); o.w = f2bf(v.w);
  *(ushort4*)(pwb + i) = o;
}

// ---------------- lag scores ----------------
__global__ __launch_bounds__(256) void k_scores(const float* __restrict__ xm,
                                                float* __restrict__ scores) {
  __shared__ float xs[2048];
  int b = blockIdx.x, tid = threadIdx.x;
  const float4* src = (const float4*)(xm + b * 2048);
  float4* dst = (float4*)xs;
  for (int i = tid; i < 512; i += 256) dst[i] = src[i];
  __syncthreads();
  int wid = tid >> 6, lane = tid & 63;
  for (int j = 0; j < 8; ++j) {
    int li = wid * 8 + j;
    int lag = LAGS_C[li];
    int n = 2048 - lag;
    float p = 0.f;
    for (int t = lane; t < n; t += 64) p += xs[t] * xs[t + lag];
#pragma unroll
    for (int off = 32; off; off >>= 1) p += __shfl_xor(p, off, 64);
    if (lane == 0) scores[b * 32 + li] = p / (float)n;
  }
}

// ---------------- top-5 + normalized weights ----------------
__global__ __launch_bounds__(64) void k_topk(const float* __restrict__ scores,
                                             int* __restrict__ lsel,
                                             float* __restrict__ wsel) {
  int b = threadIdx.x;
  if (b >= 32) return;
  unsigned used = 0;
  int idxs[5];
  float vals[5];
  for (int j = 0; j < 5; ++j) {
    float best = -3.402823466e38f;
    int bi = 0;
    for (int i = 0; i < 32; ++i) {
      float v = scores[b * 32 + i];
      if (!((used >> i) & 1u) && v > best) { best = v; bi = i; }
    }
    used |= 1u << bi;
    idxs[j] = bi;
    vals[j] = best;
  }
  float denom = vals[0] + vals[1] + vals[2] + vals[3] + vals[4] + 1e-6f;
  for (int j = 0; j < 5; ++j) {
    lsel[b * 5 + j] = LAGS_C[idxs[j]];
    wsel[b * 5 + j] = vals[j] / denom;
  }
}

// ---------------- fused conv/auto -> GEMM -> +x -> LN ----------------
// grid 512 (M-tiles of 128 rows), 512 threads (8 waves, 2x4 wave grid)
__global__ __launch_bounds__(512, 2) void k_main(
    const float* __restrict__ x, const float* __restrict__ cw0,
    const float* __restrict__ cw1, const float* __restrict__ cw2,
    const float* __restrict__ pb, const float* __restrict__ lng,
    const float* __restrict__ lnb, const unsigned short* __restrict__ pwb,
    const int* __restrict__ lsel, const float* __restrict__ wsel,
    float* __restrict__ out) {
  __shared__ __align__(16) char smem[64768];
  unsigned short* Al = (unsigned short*)smem;           // [128][32] bf16
  unsigned short* Bl = (unsigned short*)(smem + 8192);  // [512][32] bf16
  float* xs = (float*)(smem + 40960);                   // [152][36] f32
  float* cws = (float*)(smem + 62848);                  // [15][32] f32
  float2* red = (float2*)(smem + 40960);                // [128][4] (overlay xs)
  float2* rstat = (float2*)(smem + 45056);              // [128]

  const int tid = threadIdx.x;
  const int lane = tid & 63;
  const int wid = tid >> 6;
  const int wr = wid >> 2, wc = wid & 3;
  const int lr = lane & 15, g4 = lane >> 4;
  const int m0 = blockIdx.x << 7;
  const int b = m0 >> 11;
  const int l0 = m0 & 2047;
  const float* xb = x + (size_t)b * (2048 * 512);

  int lagv[5];
  float wv[5];
#pragma unroll
  for (int j = 0; j < 5; ++j) {
    lagv[j] = lsel[b * 5 + j];
    wv[j] = wsel[b * 5 + j];
  }

  f32x4 acc[4][8];
#pragma unroll
  for (int m = 0; m < 4; ++m)
#pragma unroll
    for (int n = 0; n < 8; ++n) acc[m][n] = f32x4{0.f, 0.f, 0.f, 0.f};

  for (int kc = 0; kc < 32; ++kc) {
    // ---- stage B chunk: proj_w_bf16[0:512][kc*32 : kc*32+32]
    {
      const int kb = kc << 5;
#pragma unroll 1
      for (int idx = tid; idx < 2048; idx += 512) {
        int row = idx >> 2, g = idx & 3;
        uint4 v = *(const uint4*)(pwb + row * 1024 + kb + g * 8);
        *(uint4*)(Bl + row * 32 + g * 8) = v;
      }
    }
    if (kc < 16) {
      // ---- conv branch columns d = kc*32 .. +32
      const int d0 = kc << 5;
#pragma unroll 1
      for (int idx = tid; idx < 1216; idx += 512) {  // 152 rows x 8 float4
        int row = idx >> 3, f4 = idx & 7;
        int l = l0 - 12 + row;
        float4 v = make_float4(0.f, 0.f, 0.f, 0.f);
        if (l >= 0 && l < 2048) v = *(const float4*)(xb + l * 512 + d0 + f4 * 4);
        *(float4*)(xs + row * 36 + f4 * 4) = v;
      }
      if (tid < 480) {  // 15 taps x 32 channels
        int ch = tid & 31, tap = tid >> 5;
        int d = d0 + ch;
        float v;
        if (tap < 3) v = cw0[d * 3 + tap];
        else if (tap < 8) v = cw1[d * 5 + tap - 3];
        else v = cw2[d * 7 + tap - 8];
        cws[tap * 32 + ch] = v;
      }
      __syncthreads();
      {
        const int r = tid >> 2, cg = tid & 3;
        float a0 = 0, a1 = 0, a2 = 0, a3 = 0, a4 = 0, a5 = 0, a6 = 0, a7 = 0;
        constexpr int COFF[15] = {-1, 0, 1, -4, -2, 0, 2, 4, -12, -8, -4, 0, 4, 8, 12};
#pragma unroll
        for (int tap = 0; tap < 15; ++tap) {
          const float* xp = xs + (r + 12 + COFF[tap]) * 36 + cg * 8;
          float4 xlo = *(const float4*)xp;
          float4 xhi = *(const float4*)(xp + 4);
          const float* wp = cws + tap * 32 + cg * 8;
          float4 wlo = *(const float4*)wp;
          float4 whi = *(const float4*)(wp + 4);
          a0 = fmaf(wlo.x, xlo.x, a0); a1 = fmaf(wlo.y, xlo.y, a1);
          a2 = fmaf(wlo.z, xlo.z, a2); a3 = fmaf(wlo.w, xlo.w, a3);
          a4 = fmaf(whi.x, xhi.x, a4); a5 = fmaf(whi.y, xhi.y, a5);
          a6 = fmaf(whi.z, xhi.z, a6); a7 = fmaf(whi.w, xhi.w, a7);
        }
        uint4 o;
        o.x = pk2(a0, a1); o.y = pk2(a2, a3); o.z = pk2(a4, a5); o.w = pk2(a6, a7);
        *(uint4*)(Al + r * 32 + cg * 8) = o;
      }
    } else {
      // ---- autocorr branch columns d = (kc-16)*32 .. +32
      const int d0 = (kc - 16) << 5;
      const int r = tid >> 2, cg = tid & 3;
      const int l = l0 + r;
      float a0 = 0, a1 = 0, a2 = 0, a3 = 0, a4 = 0, a5 = 0, a6 = 0, a7 = 0;
#pragma unroll
      for (int j = 0; j < 5; ++j) {
        int sl = (l - lagv[j]) & 2047;  // circular roll within batch
        const float* xp = xb + sl * 512 + d0 + cg * 8;
        float4 lo = *(const float4*)xp;
        float4 hi = *(const float4*)(xp + 4);
        float w = wv[j];
        a0 = fmaf(w, lo.x, a0); a1 = fmaf(w, lo.y, a1);
        a2 = fmaf(w, lo.z, a2); a3 = fmaf(w, lo.w, a3);
        a4 = fmaf(w, hi.x, a4); a5 = fmaf(w, hi.y, a5);
        a6 = fmaf(w, hi.z, a6); a7 = fmaf(w, hi.w, a7);
      }
      uint4 o;
      o.x = pk2(a0, a1); o.y = pk2(a2, a3); o.z = pk2(a4, a5); o.w = pk2(a6, a7);
      *(uint4*)(Al + r * 32 + cg * 8) = o;
    }
    __syncthreads();
    // ---- MFMA: acc[m][n] += A(16x32) x B(32x16)
    {
      s16x8 af[4];
#pragma unroll
      for (int m = 0; m < 4; ++m)
        af[m] = *(const s16x8*)(Al + (wr * 64 + m * 16 + lr) * 32 + g4 * 8);
#pragma unroll
      for (int n = 0; n < 8; ++n) {
        s16x8 bfg = *(const s16x8*)(Bl + (wc * 128 + n * 16 + lr) * 32 + g4 * 8);
#pragma unroll
        for (int m = 0; m < 4; ++m) acc[m][n] = mfma16(af[m], bfg, acc[m][n]);
      }
    }
    __syncthreads();
  }

  // ---- epilogue: h = x + (y + bias); LayerNorm over D=512; store
  float pbv[8], gv[8], bv[8];
#pragma unroll
  for (int n = 0; n < 8; ++n) {
    int c = wc * 128 + n * 16 + lr;
    pbv[n] = pb[c];
    gv[n] = lng[c];
    bv[n] = lnb[c];
  }
#pragma unroll
  for (int m = 0; m < 4; ++m) {
#pragma unroll
    for (int reg = 0; reg < 4; ++reg) {
      int row = wr * 64 + m * 16 + g4 * 4 + reg;
      const float* xp = xb + (l0 + row) * 512 + wc * 128 + lr;
      float s1 = 0.f, s2 = 0.f;
#pragma unroll
      for (int n = 0; n < 8; ++n) {
        float h = acc[m][n][reg] + pbv[n] + xp[n * 16];
        acc[m][n][reg] = h;
        s1 += h;
        s2 += h * h;
      }
#pragma unroll
      for (int off = 1; off < 16; off <<= 1) {
        s1 += __shfl_xor(s1, off, 64);
        s2 += __shfl_xor(s2, off, 64);
      }
      if (lr == 0) red[row * 4 + wc] = make_float2(s1, s2);
    }
  }
  __syncthreads();
  if (tid < 128) {
    float s1 = 0.f, s2 = 0.f;
#pragma unroll
    for (int w4 = 0; w4 < 4; ++w4) {
      float2 p = red[tid * 4 + w4];
      s1 += p.x;
      s2 += p.y;
    }
    float mu = s1 * (1.f / 512.f);
    float var = s2 * (1.f / 512.f) - mu * mu;
    rstat[tid] = make_float2(mu, rsqrtf(var + 1e-5f));
  }
  __syncthreads();
#pragma unroll
  for (int m = 0; m < 4; ++m) {
#pragma unroll
    for (int reg = 0; reg < 4; ++reg) {
      int row = wr * 64 + m * 16 + g4 * 4 + reg;
      float2 st = rstat[row];
      float* op = out + (size_t)(m0 + row) * 512 + wc * 128 + lr;
#pragma unroll
      for (int n = 0; n < 8; ++n)
        op[n * 16] = (acc[m][n][reg] - st.x) * st.y * gv[n] + bv[n];
    }
  }
}

extern "C" void kernel_launch(void* const* d_in, const int* in_sizes, int n_in,
                              void* d_out, int out_size, void* d_ws, size_t ws_size,
                              hipStream_t stream) {
  const float* x = (const float*)d_in[0];
  const float* cw0 = (const float*)d_in[1];
  const float* cw1 = (const float*)d_in[2];
  const float* cw2 = (const float*)d_in[3];
  const float* pw = (const float*)d_in[4];
  const float* pb = (const float*)d_in[5];
  const float* lng = (const float*)d_in[6];
  const float* lnb = (const float*)d_in[7];
  float* out = (float*)d_out;

  char* ws = (char*)d_ws;
  float* xm = (float*)ws;                                // 65536 f32 (256 KB)
  float* scores = (float*)(ws + 262144);                 // 32x32 f32
  int* lsel = (int*)(ws + 266240);                       // 32x5 int
  float* wsel = (float*)(ws + 266880);                   // 32x5 f32
  unsigned short* pwb = (unsigned short*)(ws + 267520);  // 512x1024 bf16 (1 MB)

  k_mean<<<16384, 256, 0, stream>>>(x, xm);
  k_cvt<<<512, 256, 0, stream>>>(pw, pwb);
  k_scores<<<32, 256, 0, stream>>>(xm, scores);
  k_topk<<<1, 64, 0, stream>>>(scores, lsel, wsel);
  k_main<<<512, 512, 0, stream>>>(x, cw0, cw1, cw2, pb, lng, lnb, pwb, lsel, wsel, out);
}

// Round 2
// 472.929 us; speedup vs baseline: 1.6466x; 1.6466x over previous
//
#include <hip/hip_runtime.h>

#define DEVI __device__ __forceinline__

typedef __attribute__((ext_vector_type(8))) short s16x8;
typedef __attribute__((ext_vector_type(4))) float f32x4;

// np.linspace(1, 168, 32).astype(int64)
__device__ __constant__ int LAGS_C[32] = {
    1,6,11,17,22,27,33,38,44,49,54,60,65,71,76,81,
    87,92,97,103,108,114,119,124,130,135,141,146,151,157,162,168};

DEVI unsigned short f2bf(float f) {
  unsigned u = __float_as_uint(f);
  return (unsigned short)((u + 0x7FFFu + ((u >> 16) & 1u)) >> 16);
}
DEVI unsigned pk2(float a, float b) {
  return (unsigned)f2bf(a) | ((unsigned)f2bf(b) << 16);
}

DEVI f32x4 mfma16(s16x8 a, s16x8 b, f32x4 c) {
  asm("v_mfma_f32_16x16x32_bf16 %0, %1, %2, %0" : "+v"(c) : "v"(a), "v"(b));
  return c;
}

DEVI void gl_lds16(const void* g, void* l) {
  __builtin_amdgcn_global_load_lds(
      (const __attribute__((address_space(1))) unsigned int*)g,
      (__attribute__((address_space(3))) unsigned int*)l, 16, 0, 0);
}

// ---------------- xm = mean over D ----------------
__global__ __launch_bounds__(256) void k_mean(const float* __restrict__ x,
                                              float* __restrict__ xm) {
  int row = blockIdx.x * 4 + (threadIdx.x >> 6);
  int lane = threadIdx.x & 63;
  const float4* p = (const float4*)(x + (size_t)row * 512 + lane * 8);
  float4 a = p[0], bq = p[1];
  float s = a.x + a.y + a.z + a.w + bq.x + bq.y + bq.z + bq.w;
#pragma unroll
  for (int off = 32; off; off >>= 1) s += __shfl_xor(s, off, 64);
  if (lane == 0) xm[row] = s * (1.0f / 512.0f);
}

// ---------------- proj_w fp32 -> bf16 ----------------
__global__ __launch_bounds__(256) void k_cvt(const float* __restrict__ pw,
                                             unsigned short* __restrict__ pwb) {
  int i = (blockIdx.x * 256 + threadIdx.x) * 4;
  float4 v = *(const float4*)(pw + i);
  ushort4 o;
  o.x = f2bf(v.x); o.y = f2bf(v.y); o.z = f2bf(v.z); o.w = f2bf(v.w);
  *(ushort4*)(pwb + i) = o;
}

// ---------------- lag scores ----------------
__global__ __launch_bounds__(256) void k_scores(const float* __restrict__ xm,
                                                float* __restrict__ scores) {
  __shared__ float xs[2048];
  int b = blockIdx.x, tid = threadIdx.x;
  const float4* src = (const float4*)(xm + b * 2048);
  float4* dst = (float4*)xs;
  for (int i = tid; i < 512; i += 256) dst[i] = src[i];
  __syncthreads();
  int wid = tid >> 6, lane = tid & 63;
  for (int j = 0; j < 8; ++j) {
    int li = wid * 8 + j;
    int lag = LAGS_C[li];
    int n = 2048 - lag;
    float p = 0.f;
    for (int t = lane; t < n; t += 64) p += xs[t] * xs[t + lag];
#pragma unroll
    for (int off = 32; off; off >>= 1) p += __shfl_xor(p, off, 64);
    if (lane == 0) scores[b * 32 + li] = p / (float)n;
  }
}

// ---------------- top-5 + normalized weights ----------------
__global__ __launch_bounds__(64) void k_topk(const float* __restrict__ scores,
                                             int* __restrict__ lsel,
                                             float* __restrict__ wsel) {
  int b = threadIdx.x;
  if (b >= 32) return;
  unsigned used = 0;
  int idxs[5];
  float vals[5];
  for (int j = 0; j < 5; ++j) {
    float best = -3.402823466e38f;
    int bi = 0;
    for (int i = 0; i < 32; ++i) {
      float v = scores[b * 32 + i];
      if (!((used >> i) & 1u) && v > best) { best = v; bi = i; }
    }
    used |= 1u << bi;
    idxs[j] = bi;
    vals[j] = best;
  }
  float denom = vals[0] + vals[1] + vals[2] + vals[3] + vals[4] + 1e-6f;
  for (int j = 0; j < 5; ++j) {
    lsel[b * 5 + j] = LAGS_C[idxs[j]];
    wsel[b * 5 + j] = vals[j] / denom;
  }
}

// ---------------- A-matrix build: [y_conv | y_auto] in bf16 ----------------
// block: 256 threads; tile = 64 L-rows x 128 channels of one batch
// grid per chunk: bs * 32 * 4 blocks
__global__ __launch_bounds__(256) void k_prep(
    const float* __restrict__ x, const float* __restrict__ cw0,
    const float* __restrict__ cw1, const float* __restrict__ cw2,
    const int* __restrict__ lsel, const float* __restrict__ wsel,
    unsigned short* __restrict__ Ab, int b0) {
  __shared__ float xs[88][128];
  __shared__ float cws[15][128];
  const int tid = threadIdx.x;
  const int brel = blockIdx.x >> 7;
  const int t = blockIdx.x & 127;
  const int rt = t >> 2, chg = t & 3;
  const int b = b0 + brel;
  const int l0 = rt << 6;
  const int d0 = chg << 7;
  const float* xb = x + (size_t)b * (2048 * 512);

  for (int idx = tid; idx < 88 * 32; idx += 256) {
    int row = idx >> 5, c4 = idx & 31;
    int l = l0 - 12 + row;
    float4 v = make_float4(0.f, 0.f, 0.f, 0.f);
    if (l >= 0 && l < 2048) v = *(const float4*)(xb + (size_t)l * 512 + d0 + c4 * 4);
    *(float4*)(&xs[row][c4 * 4]) = v;
  }
  for (int idx = tid; idx < 15 * 128; idx += 256) {
    int tap = idx >> 7, ch = idx & 127;
    int d = d0 + ch;
    float v;
    if (tap < 3) v = cw0[d * 3 + tap];
    else if (tap < 8) v = cw1[d * 5 + (tap - 3)];
    else v = cw2[d * 7 + (tap - 8)];
    cws[tap][ch] = v;
  }
  int lag[5];
  float wv[5];
#pragma unroll
  for (int j = 0; j < 5; ++j) {
    lag[j] = lsel[b * 5 + j];
    wv[j] = wsel[b * 5 + j];
  }
  __syncthreads();

  const int ch4 = tid & 31, rbase = tid >> 5;
  constexpr int COFF[15] = {-1, 0, 1, -4, -2, 0, 2, 4, -12, -8, -4, 0, 4, 8, 12};
#pragma unroll 1
  for (int p = 0; p < 8; ++p) {
    int r = p * 8 + rbase;
    // conv from LDS
    float a0 = 0, a1 = 0, a2 = 0, a3 = 0;
#pragma unroll
    for (int tap = 0; tap < 15; ++tap) {
      float4 xv = *(const float4*)(&xs[r + 12 + COFF[tap]][ch4 * 4]);
      float4 wv4 = *(const float4*)(&cws[tap][ch4 * 4]);
      a0 = fmaf(wv4.x, xv.x, a0);
      a1 = fmaf(wv4.y, xv.y, a1);
      a2 = fmaf(wv4.z, xv.z, a2);
      a3 = fmaf(wv4.w, xv.w, a3);
    }
    unsigned short* Arow = Ab + (size_t)(brel * 2048 + l0 + r) * 1024;
    uint2 oc;
    oc.x = pk2(a0, a1);
    oc.y = pk2(a2, a3);
    *(uint2*)(Arow + d0 + ch4 * 4) = oc;
    // autocorr from global (circular roll within batch)
    float s0 = 0, s1 = 0, s2 = 0, s3 = 0;
    int l = l0 + r;
#pragma unroll
    for (int j = 0; j < 5; ++j) {
      int sl = (l - lag[j]) & 2047;
      float4 v = *(const float4*)(xb + (size_t)sl * 512 + d0 + ch4 * 4);
      float w = wv[j];
      s0 = fmaf(w, v.x, s0);
      s1 = fmaf(w, v.y, s1);
      s2 = fmaf(w, v.z, s2);
      s3 = fmaf(w, v.w, s3);
    }
    uint2 oa;
    oa.x = pk2(s0, s1);
    oa.y = pk2(s2, s3);
    *(uint2*)(Arow + 512 + d0 + ch4 * 4) = oa;
  }
}

// ---------------- GEMM + bias + residual + LN ----------------
// BM=128, BN=512, BK=32, 512 threads (8 waves 2x4), A/B dbuf, 1 barrier/K-step
__global__ __launch_bounds__(512, 1) void k_gemm(
    const unsigned short* __restrict__ Ab, const unsigned short* __restrict__ pwb,
    const float* __restrict__ x, const float* __restrict__ pb,
    const float* __restrict__ lng, const float* __restrict__ lnb,
    float* __restrict__ out, size_t mbase) {
  __shared__ __align__(16) char smem[81920];
  char* Asm = smem;            // 2 x [128][32] bf16 = 2 x 8192
  char* Bsm = smem + 16384;    // 2 x [512][32] bf16 = 2 x 32768
  float2* red = (float2*)smem;             // [128][4] overlay
  float2* rstat = (float2*)(smem + 4096);  // [128]

  const int tid = threadIdx.x;
  const int lane = tid & 63;
  const int wid = tid >> 6;
  const int wr = wid >> 2, wc = wid & 3;
  const int lr = lane & 15, g4 = lane >> 4;
  const int m0 = blockIdx.x << 7;  // chunk-local row base

  // staging constants: lane tid stages LDS row sr, linear slot tid&3;
  // source slot is XOR-swizzled so ds_read with the same swizzle is conflict-spread
  const int sr = tid >> 2;
  const int ssl = (tid & 3) ^ ((sr >> 1) & 3);
  const unsigned short* aSrc = Ab + (size_t)(m0 + sr) * 1024 + ssl * 8;
  const unsigned short* bSrc0 = pwb + (size_t)sr * 1024 + ssl * 8;

  f32x4 acc[4][8];
#pragma unroll
  for (int m = 0; m < 4; ++m)
#pragma unroll
    for (int n = 0; n < 8; ++n) acc[m][n] = f32x4{0.f, 0.f, 0.f, 0.f};

  // frag read offsets (swizzled slot; invariant across m/n since 16-row steps)
  const int swsl = (g4 ^ ((lr >> 1) & 3)) << 4;
  const int aoff = (wr * 64 + lr) * 64 + swsl;
  const int boff = (wc * 128 + lr) * 64 + swsl;

#define STAGE(bufi, kt)                                                   \
  do {                                                                    \
    gl_lds16(aSrc + (kt) * 32, Asm + (bufi) * 8192 + wid * 1024);         \
    _Pragma("unroll") for (int i = 0; i < 4; ++i)                         \
        gl_lds16(bSrc0 + (size_t)i * 131072 + (kt) * 32,                  \
                 Bsm + (bufi) * 32768 + i * 8192 + wid * 1024);           \
  } while (0)

  STAGE(0, 0);
  __syncthreads();
#pragma unroll 1
  for (int kt = 0; kt < 32; ++kt) {
    const int cur = kt & 1;
    if (kt + 1 < 32) STAGE(cur ^ 1, kt + 1);
    const char* ab = Asm + cur * 8192;
    const char* bb = Bsm + cur * 32768;
    s16x8 af[4];
#pragma unroll
    for (int m = 0; m < 4; ++m) af[m] = *(const s16x8*)(ab + aoff + m * 1024);
#pragma unroll
    for (int n = 0; n < 8; ++n) {
      s16x8 bf = *(const s16x8*)(bb + boff + n * 1024);
#pragma unroll
      for (int m = 0; m < 4; ++m) acc[m][n] = mfma16(af[m], bf, acc[m][n]);
    }
    __syncthreads();
  }
#undef STAGE

  // epilogue: h = x + (y + bias); LayerNorm over D=512; store
  float pbv[8], gv[8], bv[8];
#pragma unroll
  for (int n = 0; n < 8; ++n) {
    int c = wc * 128 + n * 16 + lr;
    pbv[n] = pb[c];
    gv[n] = lng[c];
    bv[n] = lnb[c];
  }
#pragma unroll
  for (int m = 0; m < 4; ++m) {
#pragma unroll
    for (int reg = 0; reg < 4; ++reg) {
      int row = wr * 64 + m * 16 + g4 * 4 + reg;
      const float* xp = x + (mbase + m0 + row) * 512 + wc * 128 + lr;
      float s1 = 0.f, s2 = 0.f;
#pragma unroll
      for (int n = 0; n < 8; ++n) {
        float h = acc[m][n][reg] + pbv[n] + xp[n * 16];
        acc[m][n][reg] = h;
        s1 += h;
        s2 += h * h;
      }
#pragma unroll
      for (int off = 1; off < 16; off <<= 1) {
        s1 += __shfl_xor(s1, off, 64);
        s2 += __shfl_xor(s2, off, 64);
      }
      if (lr == 0) red[row * 4 + wc] = make_float2(s1, s2);
    }
  }
  __syncthreads();
  if (tid < 128) {
    float s1 = 0.f, s2 = 0.f;
#pragma unroll
    for (int w4 = 0; w4 < 4; ++w4) {
      float2 p = red[tid * 4 + w4];
      s1 += p.x;
      s2 += p.y;
    }
    float mu = s1 * (1.f / 512.f);
    float var = s2 * (1.f / 512.f) - mu * mu;
    rstat[tid] = make_float2(mu, rsqrtf(var + 1e-5f));
  }
  __syncthreads();
#pragma unroll
  for (int m = 0; m < 4; ++m) {
#pragma unroll
    for (int reg = 0; reg < 4; ++reg) {
      int row = wr * 64 + m * 16 + g4 * 4 + reg;
      float2 st = rstat[row];
      float* op = out + (mbase + m0 + row) * 512 + wc * 128 + lr;
#pragma unroll
      for (int n = 0; n < 8; ++n)
        op[n * 16] = (acc[m][n][reg] - st.x) * st.y * gv[n] + bv[n];
    }
  }
}

extern "C" void kernel_launch(void* const* d_in, const int* in_sizes, int n_in,
                              void* d_out, int out_size, void* d_ws, size_t ws_size,
                              hipStream_t stream) {
  const float* x = (const float*)d_in[0];
  const float* cw0 = (const float*)d_in[1];
  const float* cw1 = (const float*)d_in[2];
  const float* cw2 = (const float*)d_in[3];
  const float* pw = (const float*)d_in[4];
  const float* pb = (const float*)d_in[5];
  const float* lng = (const float*)d_in[6];
  const float* lnb = (const float*)d_in[7];
  float* out = (float*)d_out;

  char* ws = (char*)d_ws;
  float* xm = (float*)ws;                                // 65536 f32 (256 KB)
  float* scores = (float*)(ws + 262144);                 // 32x32 f32
  int* lsel = (int*)(ws + 266240);                       // 32x5 int
  float* wsel = (float*)(ws + 266880);                   // 32x5 f32
  unsigned short* pwb = (unsigned short*)(ws + 267520);  // 512x1024 bf16 (1 MB)
  unsigned short* Ab = (unsigned short*)(ws + 1316096);  // A chunk (bf16)

  // chunking: A needs 32/nch batches * 2048 rows * 1024 cols * 2 B
  size_t avail = ws_size > 1316096 ? ws_size - 1316096 : 0;
  int nch = 1;
  while (nch < 32 && ((size_t)134217728 / nch) > avail) nch <<= 1;
  int bs = 32 / nch;  // batches per chunk

  k_mean<<<16384, 256, 0, stream>>>(x, xm);
  k_cvt<<<512, 256, 0, stream>>>(pw, pwb);
  k_scores<<<32, 256, 0, stream>>>(xm, scores);
  k_topk<<<1, 64, 0, stream>>>(scores, lsel, wsel);
  for (int c = 0; c < nch; ++c) {
    int b0 = c * bs;
    k_prep<<<bs * 128, 256, 0, stream>>>(x, cw0, cw1, cw2, lsel, wsel, Ab, b0);
    k_gemm<<<bs * 16, 512, 0, stream>>>(Ab, pwb, x, pb, lng, lnb, out,
                                        (size_t)b0 * 2048);
  }
}